// Round 1
// baseline (470.286 us; speedup 1.0000x reference)
//
#include <hip/hip_runtime.h>
#include <hip/hip_bf16.h>
#include <cstdint>

#define T_TOK 4096
#define H_DIM 1024
#define F_DIM 2048
#define E_NUM 8
#define BM 128
#define BK 64
#define MAXTILES 71            // max of sum(ceil(n_e/128)) with sum n_e = 8192
#define MAXROWS (MAXTILES*BM)  // 9088

typedef __attribute__((ext_vector_type(8))) short bf16x8;
typedef __attribute__((ext_vector_type(4))) float f32x4;

__device__ __forceinline__ unsigned short f2bf(float f){
  union { float f; uint32_t u; } c; c.f = f;
  uint32_t u = c.u;
  uint32_t r = (u + 0x7fffu + ((u >> 16) & 1u)) >> 16;
  return (unsigned short)r;
}

__device__ __forceinline__ void gload_lds16(const void* g, void* l){
  __builtin_amdgcn_global_load_lds(
      (const __attribute__((address_space(1))) unsigned int*)g,
      (__attribute__((address_space(3))) unsigned int*)l, 16, 0, 0);
}

// ---------------- fp32 -> bf16 convert (grid-stride, float4) ----------------
__global__ __launch_bounds__(256) void k_f2bf(const float* __restrict__ s,
                                              unsigned short* __restrict__ d, int n4){
  int i = blockIdx.x*256 + threadIdx.x;
  int stride = gridDim.x*256;
  for (; i < n4; i += stride){
    float4 v = reinterpret_cast<const float4*>(s)[i];
    ushort4 o;
    o.x = f2bf(v.x); o.y = f2bf(v.y); o.z = f2bf(v.z); o.w = f2bf(v.w);
    reinterpret_cast<ushort4*>(d)[i] = o;
  }
}

// ---------------- router: logits in fp64, top-2, renormalized weights -------
__global__ __launch_bounds__(64) void k_router(const float* __restrict__ x,
                                               const float* __restrict__ rw,
                                               int* __restrict__ counts,
                                               int* __restrict__ topi,
                                               float* __restrict__ topv){
  int t = blockIdx.x;
  int lane = threadIdx.x;
  const float* xr = x + (size_t)t*H_DIM;
  double acc[E_NUM];
#pragma unroll
  for (int e=0;e<E_NUM;e++) acc[e] = 0.0;
  for (int j=0;j<H_DIM/64;j++){
    double xv = (double)xr[lane + 64*j];
#pragma unroll
    for (int e=0;e<E_NUM;e++) acc[e] += xv * (double)rw[e*H_DIM + lane + 64*j];
  }
#pragma unroll
  for (int e=0;e<E_NUM;e++){
    double v = acc[e];
    for (int off=32; off>0; off>>=1) v += __shfl_xor(v, off, 64);
    acc[e] = v;
  }
  if (lane == 0){
    int i0 = 0; double v0 = acc[0];
    for (int e=1;e<E_NUM;e++) if (acc[e] > v0){ v0 = acc[e]; i0 = e; }
    int i1 = -1; double v1 = -1e300;
    for (int e=0;e<E_NUM;e++) if (e != i0 && acc[e] > v1){ v1 = acc[e]; i1 = e; }
    float w0 = 1.0f/(1.0f + expf((float)(v1 - v0)));  // softmax Z cancels in renorm
    topi[2*t] = i0; topi[2*t+1] = i1;
    topv[2*t] = w0; topv[2*t+1] = 1.0f - w0;
    atomicAdd(&counts[i0], 1); atomicAdd(&counts[i1], 1);
  }
}

// ---------------- per-expert padded tile offsets ----------------------------
__global__ void k_offsets(const int* __restrict__ counts,
                          int* __restrict__ tile_start, int* __restrict__ cursors){
  if (threadIdx.x == 0){
    int acc = 0;
    for (int e=0;e<E_NUM;e++){ tile_start[e] = acc; acc += (counts[e] + BM - 1)/BM; }
    tile_start[E_NUM] = acc;
  }
  if (threadIdx.x < E_NUM) cursors[threadIdx.x] = 0;
}

// ---------------- fill grouped entry lists ----------------------------------
__global__ __launch_bounds__(256) void k_fill(const int* __restrict__ topi,
                                              const int* __restrict__ tile_start,
                                              int* __restrict__ cursors,
                                              int* __restrict__ entries){
  int t = blockIdx.x*256 + threadIdx.x;
  if (t >= T_TOK) return;
#pragma unroll
  for (int k=0;k<2;k++){
    int e = topi[2*t+k];
    int pos = atomicAdd(&cursors[e], 1);
    entries[tile_start[e]*BM + pos] = 2*t + k;
  }
}

// ---------------- phase 1: gate+up grouped GEMM + SiLU ----------------------
// grid: (MAXTILES, F/64), block 256.  A = gathered x rows [128 x 64k], B1/B3 = w1/w3 [64 x 64k]
__global__ __launch_bounds__(256) void k_ffn1(const unsigned short* __restrict__ xb,
                                              const unsigned short* __restrict__ w1b,
                                              const unsigned short* __restrict__ w3b,
                                              const int* __restrict__ tile_start,
                                              const int* __restrict__ counts,
                                              const int* __restrict__ entries,
                                              unsigned short* __restrict__ hidden){
  int mt = blockIdx.x;
  if (mt >= tile_start[E_NUM]) return;
  int nt = blockIdx.y;
  int e = 0;
  for (int i=E_NUM-1;i>=0;i--) if (mt >= tile_start[i]){ e = i; break; }
  int n_e  = counts[e];
  int row0 = (mt - tile_start[e])*BM;
  int ebase = tile_start[e]*BM;

  __shared__ unsigned short lA[BM*BK];
  __shared__ unsigned short lB1[64*BK];
  __shared__ unsigned short lB3[64*BK];
  __shared__ int tok[BM];

  int tid = threadIdx.x;
  if (tid < BM){
    int gr = row0 + tid;
    int cl = gr < n_e ? gr : (n_e - 1);
    tok[tid] = entries[ebase + cl] >> 1;
  }
  __syncthreads();

  int lane = tid & 63, wid = tid >> 6;
  int wm = wid >> 1, wn = wid & 1;
  int seg = lane & 7, rsub = lane >> 3;

  const unsigned short* pA[4]; unsigned short* lAp[4];
  const unsigned short* pB1[2]; const unsigned short* pB3[2];
  unsigned short *lB1p[2], *lB3p[2];
#pragma unroll
  for (int i=0;i<4;i++){
    int rb = (wid*4 + i)*8;
    int r  = rb + rsub;
    int sc = (seg ^ (r & 7)) * 8;      // pre-swizzled global source col (bf16 elems)
    pA[i]  = xb + (size_t)tok[r]*H_DIM + sc;
    lAp[i] = lA + rb*BK;
  }
#pragma unroll
  for (int i=0;i<2;i++){
    int rb = (wid*2 + i)*8;
    int r  = rb + rsub;
    int sc = (seg ^ (r & 7)) * 8;
    pB1[i]  = w1b + ((size_t)e*F_DIM + nt*64 + r)*H_DIM + sc;
    pB3[i]  = w3b + ((size_t)e*F_DIM + nt*64 + r)*H_DIM + sc;
    lB1p[i] = lB1 + rb*BK;
    lB3p[i] = lB3 + rb*BK;
  }

  f32x4 accG[4][2], accU[4][2];
#pragma unroll
  for (int m=0;m<4;m++)
#pragma unroll
    for (int n=0;n<2;n++){ accG[m][n] = {0.f,0.f,0.f,0.f}; accU[m][n] = {0.f,0.f,0.f,0.f}; }

  int aoff[2][4], boff[2][2];
#pragma unroll
  for (int ks=0;ks<2;ks++){
    int kb = ks*64 + (lane >> 4)*16;
#pragma unroll
    for (int m=0;m<4;m++){
      int row = wm*64 + m*16 + (lane & 15);
      aoff[ks][m] = row*128 + (kb ^ ((row & 7) << 4));
    }
#pragma unroll
    for (int n=0;n<2;n++){
      int row = wn*32 + n*16 + (lane & 15);
      boff[ks][n] = row*128 + (kb ^ ((row & 7) << 4));
    }
  }

  for (int kk=0; kk<H_DIM; kk+=BK){
#pragma unroll
    for (int i=0;i<4;i++) gload_lds16(pA[i] + kk, lAp[i]);
#pragma unroll
    for (int i=0;i<2;i++) gload_lds16(pB1[i] + kk, lB1p[i]);
#pragma unroll
    for (int i=0;i<2;i++) gload_lds16(pB3[i] + kk, lB3p[i]);
    __syncthreads();
#pragma unroll
    for (int ks=0;ks<2;ks++){
      bf16x8 a[4], b1[2], b3[2];
#pragma unroll
      for (int m=0;m<4;m++) a[m]  = *(const bf16x8*)((const char*)lA  + aoff[ks][m]);
#pragma unroll
      for (int n=0;n<2;n++){ b1[n] = *(const bf16x8*)((const char*)lB1 + boff[ks][n]);
                             b3[n] = *(const bf16x8*)((const char*)lB3 + boff[ks][n]); }
#pragma unroll
      for (int m=0;m<4;m++)
#pragma unroll
        for (int n=0;n<2;n++){
          accG[m][n] = __builtin_amdgcn_mfma_f32_16x16x32_bf16(a[m], b1[n], accG[m][n], 0,0,0);
          accU[m][n] = __builtin_amdgcn_mfma_f32_16x16x32_bf16(a[m], b3[n], accU[m][n], 0,0,0);
        }
    }
    __syncthreads();
  }

#pragma unroll
  for (int m=0;m<4;m++){
#pragma unroll
    for (int n=0;n<2;n++){
      f32x4 g = accG[m][n], u = accU[m][n];
      int col = nt*64 + wn*32 + n*16 + (lane & 15);
#pragma unroll
      for (int j=0;j<4;j++){
        int rit = wm*64 + m*16 + ((lane >> 4) & 3)*4 + j;
        if (row0 + rit < n_e){
          float gg = g[j], uu = u[j];
          float h = (gg / (1.f + expf(-gg))) * uu;   // silu(gate)*up
          hidden[(size_t)(ebase + row0 + rit)*F_DIM + col] = f2bf(h);
        }
      }
    }
  }
}

// ---------------- phase 2: down-proj grouped GEMM + weighted combine --------
// grid: (MAXTILES, H/128), block 256.  A = hidden rows [128 x 64k], B = w2 [128 x 64k]
__global__ __launch_bounds__(256) void k_ffn2(const unsigned short* __restrict__ hidden,
                                              const unsigned short* __restrict__ w2b,
                                              const int* __restrict__ tile_start,
                                              const int* __restrict__ counts,
                                              const int* __restrict__ entries,
                                              const float* __restrict__ topv,
                                              float* __restrict__ out){
  int mt = blockIdx.x;
  if (mt >= tile_start[E_NUM]) return;
  int nt = blockIdx.y;
  int e = 0;
  for (int i=E_NUM-1;i>=0;i--) if (mt >= tile_start[i]){ e = i; break; }
  int n_e  = counts[e];
  int row0 = (mt - tile_start[e])*BM;
  int ebase = tile_start[e]*BM;

  __shared__ unsigned short lA[BM*BK];
  __shared__ unsigned short lB[BM*BK];

  int tid = threadIdx.x, lane = tid & 63, wid = tid >> 6;
  int wm = wid >> 1, wn = wid & 1;
  int seg = lane & 7, rsub = lane >> 3;

  const unsigned short* pA[4]; const unsigned short* pB[4];
  unsigned short *lAp[4], *lBp[4];
#pragma unroll
  for (int i=0;i<4;i++){
    int rb = (wid*4 + i)*8;
    int r  = rb + rsub;
    int sc = (seg ^ (r & 7)) * 8;
    pA[i]  = hidden + (size_t)(ebase + row0 + r)*F_DIM + sc;
    pB[i]  = w2b + ((size_t)e*H_DIM + nt*BM + r)*F_DIM + sc;
    lAp[i] = lA + rb*BK;
    lBp[i] = lB + rb*BK;
  }

  f32x4 acc[4][4];
#pragma unroll
  for (int m=0;m<4;m++)
#pragma unroll
    for (int n=0;n<4;n++) acc[m][n] = {0.f,0.f,0.f,0.f};

  int aoff[2][4], boff[2][4];
#pragma unroll
  for (int ks=0;ks<2;ks++){
    int kb = ks*64 + (lane >> 4)*16;
#pragma unroll
    for (int m=0;m<4;m++){
      int row = wm*64 + m*16 + (lane & 15);
      aoff[ks][m] = row*128 + (kb ^ ((row & 7) << 4));
    }
#pragma unroll
    for (int n=0;n<4;n++){
      int row = wn*64 + n*16 + (lane & 15);
      boff[ks][n] = row*128 + (kb ^ ((row & 7) << 4));
    }
  }

  for (int kk=0; kk<F_DIM; kk+=BK){
#pragma unroll
    for (int i=0;i<4;i++) gload_lds16(pA[i] + kk, lAp[i]);
#pragma unroll
    for (int i=0;i<4;i++) gload_lds16(pB[i] + kk, lBp[i]);
    __syncthreads();
#pragma unroll
    for (int ks=0;ks<2;ks++){
      bf16x8 a[4], b[4];
#pragma unroll
      for (int m=0;m<4;m++) a[m] = *(const bf16x8*)((const char*)lA + aoff[ks][m]);
#pragma unroll
      for (int n=0;n<4;n++) b[n] = *(const bf16x8*)((const char*)lB + boff[ks][n]);
#pragma unroll
      for (int m=0;m<4;m++)
#pragma unroll
        for (int n=0;n<4;n++)
          acc[m][n] = __builtin_amdgcn_mfma_f32_16x16x32_bf16(a[m], b[n], acc[m][n], 0,0,0);
    }
    __syncthreads();
  }

#pragma unroll
  for (int m=0;m<4;m++){
#pragma unroll
    for (int j=0;j<4;j++){
      int rit = wm*64 + m*16 + ((lane >> 4) & 3)*4 + j;
      int gr  = row0 + rit;
      if (gr < n_e){
        int packed = entries[ebase + gr];
        int t = packed >> 1;
        float w = topv[packed];
#pragma unroll
        for (int n=0;n<4;n++){
          int col = nt*BM + wn*64 + n*16 + (lane & 15);
          atomicAdd(&out[(size_t)t*H_DIM + col], w * acc[m][n][j]);
        }
      }
    }
  }
}

// ---------------------------------------------------------------------------
extern "C" void kernel_launch(void* const* d_in, const int* in_sizes, int n_in,
                              void* d_out, int out_size, void* d_ws, size_t ws_size,
                              hipStream_t stream){
  const float* x  = (const float*)d_in[0];
  const float* rw = (const float*)d_in[1];
  const float* w1 = (const float*)d_in[2];
  const float* w2 = (const float*)d_in[3];
  const float* w3 = (const float*)d_in[4];
  float* out = (float*)d_out;

  char* ws = (char*)d_ws;
  size_t off = 0;
  unsigned short* xb  = (unsigned short*)(ws + off); off += (size_t)T_TOK*H_DIM*2;
  unsigned short* w1b = (unsigned short*)(ws + off); off += (size_t)E_NUM*F_DIM*H_DIM*2;
  unsigned short* w3b = (unsigned short*)(ws + off); off += (size_t)E_NUM*F_DIM*H_DIM*2;
  unsigned short* w2b = (unsigned short*)(ws + off); off += (size_t)E_NUM*H_DIM*F_DIM*2;
  unsigned short* hidden = (unsigned short*)(ws + off); off += (size_t)MAXROWS*F_DIM*2;
  int*   counts     = (int*)(ws + off); off += 64;
  int*   tile_start = (int*)(ws + off); off += 64;
  int*   cursors    = (int*)(ws + off); off += 64;
  int*   topi       = (int*)(ws + off); off += (size_t)T_TOK*2*4;
  float* topv       = (float*)(ws + off); off += (size_t)T_TOK*2*4;
  int*   entries    = (int*)(ws + off); off += (size_t)MAXROWS*4;

  hipMemsetAsync(counts, 0, 32, stream);
  hipMemsetAsync(out, 0, (size_t)out_size*sizeof(float), stream);

  k_f2bf<<<2048, 256, 0, stream>>>(x,  xb,  T_TOK*H_DIM/4);
  k_f2bf<<<2048, 256, 0, stream>>>(w1, w1b, E_NUM*F_DIM*H_DIM/4);
  k_f2bf<<<2048, 256, 0, stream>>>(w3, w3b, E_NUM*F_DIM*H_DIM/4);
  k_f2bf<<<2048, 256, 0, stream>>>(w2, w2b, E_NUM*H_DIM*F_DIM/4);

  k_router<<<T_TOK, 64, 0, stream>>>(x, rw, counts, topi, topv);
  k_offsets<<<1, 64, 0, stream>>>(counts, tile_start, cursors);
  k_fill<<<T_TOK/256, 256, 0, stream>>>(topi, tile_start, cursors, entries);

  k_ffn1<<<dim3(MAXTILES, F_DIM/64), 256, 0, stream>>>(xb, w1b, w3b, tile_start, counts, entries, hidden);
  k_ffn2<<<dim3(MAXTILES, H_DIM/128), 256, 0, stream>>>(hidden, w2b, tile_start, counts, entries, topv, out);
}

// Round 2
// 423.104 us; speedup vs baseline: 1.1115x; 1.1115x over previous
//
#include <hip/hip_runtime.h>
#include <hip/hip_bf16.h>
#include <cstdint>

#define T_TOK 4096
#define H_DIM 1024
#define F_DIM 2048
#define E_NUM 8
#define MAXT256 39
#define MAXT128 71
#define MAXROWS (MAXT256*256)   // 9984 padded entry rows

typedef __attribute__((ext_vector_type(8))) short bf16x8;
typedef __attribute__((ext_vector_type(4))) float f32x4;

__device__ __forceinline__ unsigned short f2bf(float f){
  union { float f; uint32_t u; } c; c.f = f;
  uint32_t u = c.u;
  uint32_t r = (u + 0x7fffu + ((u >> 16) & 1u)) >> 16;
  return (unsigned short)r;
}

// ---------------- fp32 -> bf16 convert (grid-stride, float4) ----------------
__global__ __launch_bounds__(256) void k_f2bf(const float* __restrict__ s,
                                              unsigned short* __restrict__ d, int n4){
  int i = blockIdx.x*256 + threadIdx.x;
  int stride = gridDim.x*256;
  for (; i < n4; i += stride){
    float4 v = reinterpret_cast<const float4*>(s)[i];
    ushort4 o;
    o.x = f2bf(v.x); o.y = f2bf(v.y); o.z = f2bf(v.z); o.w = f2bf(v.w);
    reinterpret_cast<ushort4*>(d)[i] = o;
  }
}

// ---------------- router: logits in fp64, top-2, renormalized weights -------
__global__ __launch_bounds__(64) void k_router(const float* __restrict__ x,
                                               const float* __restrict__ rw,
                                               int* __restrict__ counts,
                                               int* __restrict__ topi,
                                               float* __restrict__ topv){
  int t = blockIdx.x;
  int lane = threadIdx.x;
  const float* xr = x + (size_t)t*H_DIM;
  double acc[E_NUM];
#pragma unroll
  for (int e=0;e<E_NUM;e++) acc[e] = 0.0;
  for (int j=0;j<H_DIM/64;j++){
    double xv = (double)xr[lane + 64*j];
#pragma unroll
    for (int e=0;e<E_NUM;e++) acc[e] += xv * (double)rw[e*H_DIM + lane + 64*j];
  }
#pragma unroll
  for (int e=0;e<E_NUM;e++){
    double v = acc[e];
    for (int off=32; off>0; off>>=1) v += __shfl_xor(v, off, 64);
    acc[e] = v;
  }
  if (lane == 0){
    int i0 = 0; double v0 = acc[0];
    for (int e=1;e<E_NUM;e++) if (acc[e] > v0){ v0 = acc[e]; i0 = e; }
    int i1 = -1; double v1 = -1e300;
    for (int e=0;e<E_NUM;e++) if (e != i0 && acc[e] > v1){ v1 = acc[e]; i1 = e; }
    float w0 = 1.0f/(1.0f + expf((float)(v1 - v0)));  // softmax Z cancels in renorm
    topi[2*t] = i0; topi[2*t+1] = i1;
    topv[2*t] = w0; topv[2*t+1] = 1.0f - w0;
    atomicAdd(&counts[i0], 1); atomicAdd(&counts[i1], 1);
  }
}

// ---------------- per-expert padded tile offsets (128- and 256-granular) ----
__global__ void k_offsets(const int* __restrict__ counts,
                          int* __restrict__ ts128, int* __restrict__ ts256,
                          int* __restrict__ cursors){
  if (threadIdx.x == 0){
    int a = 0, b = 0;
    for (int e=0;e<E_NUM;e++){
      ts128[e] = a; ts256[e] = b;
      a += (counts[e] + 127) >> 7;
      b += (counts[e] + 255) >> 8;
    }
    ts128[E_NUM] = a; ts256[E_NUM] = b;
  }
  if (threadIdx.x < E_NUM) cursors[threadIdx.x] = 0;
}

// ---------------- fill grouped entry lists (256-granular layout) ------------
__global__ __launch_bounds__(256) void k_fill(const int* __restrict__ topi,
                                              const int* __restrict__ ts256,
                                              int* __restrict__ cursors,
                                              int* __restrict__ entries){
  int t = blockIdx.x*256 + threadIdx.x;
  if (t >= T_TOK) return;
#pragma unroll
  for (int k=0;k<2;k++){
    int e = topi[2*t+k];
    int pos = atomicAdd(&cursors[e], 1);
    entries[ts256[e]*256 + pos] = 2*t + k;
  }
}

// ---------------- phase 1: 8-phase 256x256 grouped GEMM + SiLU --------------
// C tile = 256 token-rows x 256 cols (interleaved per 32: even 32-blk = gate/w1,
// odd 32-blk = up/w3, covering f-range nt*128..+128). A halves interleave rows
// by bit6; B half0 = w1 rows, half1 = w3 rows (f = within-half row index).
// LDS: [dbuf 2][A0,A1,B0,B1][128x64 bf16] = 128 KiB, dynamic.

#define GLD(src, dst_us) __builtin_amdgcn_global_load_lds( \
  (const __attribute__((address_space(1))) unsigned int*)(src), \
  (__attribute__((address_space(3))) unsigned int*)(lds + (dst_us)), 16, 0, 0)

#define STG(X, s0, s1, dbS, kS) do{ \
  GLD((s0) + (kS)*64, (dbS)*32768 + (X)*8192 + dstb0); \
  GLD((s1) + (kS)*64, (dbS)*32768 + (X)*8192 + dstb1); }while(0)

#define LDA(db, QR) do{ const char* p_ = (const char*)lds + ((db)*4 + (QR))*16384; \
  _Pragma("unroll") for (int m_=0;m_<4;m_++) \
  _Pragma("unroll") for (int ks_=0;ks_<2;ks_++) \
    a[m_][ks_] = *(const bf16x8*)(p_ + aoff[m_][ks_]); }while(0)

#define LDB(db, QC, breg) do{ const char* p_ = (const char*)lds + ((db)*4 + 2 + (QC))*16384; \
  _Pragma("unroll") for (int n_=0;n_<2;n_++) \
  _Pragma("unroll") for (int ks_=0;ks_<2;ks_++) \
    breg[n_][ks_] = *(const bf16x8*)(p_ + boff[n_][ks_]); }while(0)

#define MM(QR, QC, breg) do{ \
  _Pragma("unroll") for (int m_=0;m_<4;m_++) \
  _Pragma("unroll") for (int n_=0;n_<2;n_++) \
  _Pragma("unroll") for (int ks_=0;ks_<2;ks_++) \
    acc[QR][QC][m_][n_] = __builtin_amdgcn_mfma_f32_16x16x32_bf16(a[m_][ks_], breg[n_][ks_], acc[QR][QC][m_][n_], 0,0,0); }while(0)

#define SYNC1 do{ __builtin_amdgcn_s_barrier(); \
  asm volatile("s_waitcnt lgkmcnt(0)" ::: "memory"); \
  __builtin_amdgcn_sched_barrier(0); \
  __builtin_amdgcn_s_setprio(1); }while(0)

#define SYNC2 do{ __builtin_amdgcn_s_setprio(0); \
  __builtin_amdgcn_s_barrier(); \
  __builtin_amdgcn_sched_barrier(0); }while(0)

#define VM4 asm volatile("s_waitcnt vmcnt(4)" ::: "memory")
#define VM2 asm volatile("s_waitcnt vmcnt(2)" ::: "memory")
#define VM0 asm volatile("s_waitcnt vmcnt(0)" ::: "memory")

__global__ __launch_bounds__(512) void k_ffn1(const unsigned short* __restrict__ xb,
                                              const unsigned short* __restrict__ w1b,
                                              const unsigned short* __restrict__ w3b,
                                              const int* __restrict__ ts256,
                                              const int* __restrict__ counts,
                                              const int* __restrict__ entries,
                                              unsigned short* __restrict__ hidden){
  extern __shared__ unsigned short lds[];   // 2*4*8192 ushorts = 128 KiB
  int flat = blockIdx.x;
  int nw = (flat & 7)*78 + (flat >> 3);     // 624 = 8*78 bijective XCD chunking
  int tile = nw % MAXT256;
  int nt   = nw / MAXT256;
  if (tile >= ts256[E_NUM]) return;
  int e = 0;
  for (int i=E_NUM-1;i>=0;i--) if (tile >= ts256[i]){ e = i; break; }
  int n_e  = counts[e];
  int row0 = (tile - ts256[e])*256;
  int ebase = ts256[e]*256;

  int tid = threadIdx.x, lane = tid & 63, wid = tid >> 6;
  int wm = wid >> 2, wn = wid & 3;          // 2 x 4 wave grid

  // --- staging source pointers (pre-swizzled global col) ---
  const unsigned short* sA[2][2];
  const unsigned short* sB[2][2];
#pragma unroll
  for (int h=0;h<2;h++){
#pragma unroll
    for (int i=0;i<2;i++){
      int idx = i*512 + tid;
      int r = idx >> 3, seg = idx & 7;
      int sc = (seg ^ (r & 7))*8;
      int br = ((r>>6)<<7) | (h<<6) | (r & 63);   // interleaved A halves (bit6)
      int rr = row0 + br; rr = rr < n_e ? rr : (n_e - 1);
      int tokr = entries[ebase + rr] >> 1;
      sA[h][i] = xb + (size_t)tokr*H_DIM + sc;
      const unsigned short* w = h ? w3b : w1b;    // B half0=w1(gate), half1=w3(up)
      sB[h][i] = w + ((size_t)e*F_DIM + nt*128 + r)*H_DIM + sc;
    }
  }
  int dstb0 = wid*512;          // ushort units, wave-uniform LDS dest bases
  int dstb1 = 4096 + wid*512;

  // --- fragment read offsets (bytes within a 16 KiB half) ---
  int aoff[4][2], boff[2][2];
#pragma unroll
  for (int m=0;m<4;m++){
    int ia = wm*64 + m*16 + (lane & 15);
#pragma unroll
    for (int ks=0;ks<2;ks++)
      aoff[m][ks] = ia*128 + ((ks*64 + (lane>>4)*16) ^ ((ia & 7) << 4));
  }
#pragma unroll
  for (int n=0;n<2;n++){
    int ib = wn*32 + n*16 + (lane & 15);
#pragma unroll
    for (int ks=0;ks<2;ks++)
      boff[n][ks] = ib*128 + ((ks*64 + (lane>>4)*16) ^ ((ib & 7) << 4));
  }

  f32x4 acc[2][2][4][2];
#pragma unroll
  for (int qr=0;qr<2;qr++)
#pragma unroll
  for (int qc=0;qc<2;qc++)
#pragma unroll
  for (int m=0;m<4;m++)
#pragma unroll
  for (int n=0;n<2;n++) acc[qr][qc][m][n] = {0.f,0.f,0.f,0.f};

  bf16x8 a[4][2], bA[2][2], bB[2][2];

  // --- prologue: stage tile 0 in need order A0,B0,B1,A1 ---
  STG(0, sA[0][0], sA[0][1], 0, 0);
  STG(2, sB[0][0], sB[0][1], 0, 0);
  STG(3, sB[1][0], sB[1][1], 0, 0);
  STG(1, sA[1][0], sA[1][1], 0, 0);
  VM4;
  __builtin_amdgcn_s_barrier();

  // --- main loop: 15 tiles with prefetch, 4 phases each ---
  for (int T=0; T<15; ++T){
    int db = T & 1, dbS = db ^ 1, kS = T + 1;
    // q0: quadrant (A0,B0)
    LDA(db, 0); LDB(db, 0, bA);
    STG(0, sA[0][0], sA[0][1], dbS, kS);
    VM4; SYNC1; MM(0,0,bA); SYNC2;
    // q1: (A0,B1) — reuse a
    LDB(db, 1, bB);
    STG(2, sB[0][0], sB[0][1], dbS, kS);
    VM4; SYNC1; MM(0,1,bB); SYNC2;
    // q2: (A1,B0) — reuse bA
    LDA(db, 1);
    STG(3, sB[1][0], sB[1][1], dbS, kS);
    VM4; SYNC1; MM(1,0,bA); SYNC2;
    // q3: (A1,B1) — reuse a, bB
    STG(1, sA[1][0], sA[1][1], dbS, kS);
    VM4; SYNC1; MM(1,1,bB); SYNC2;
  }
  // --- epilogue tile 15 (db=1): drain 4 -> 2 -> 0 ---
  LDA(1,0); LDB(1,0,bA); VM2; SYNC1; MM(0,0,bA); SYNC2;
  LDB(1,1,bB);           VM0; SYNC1; MM(0,1,bB); SYNC2;
  LDA(1,1);                   SYNC1; MM(1,0,bA); SYNC2;
                              SYNC1; MM(1,1,bB); SYNC2;

  // --- SiLU epilogue: gate=acc[qr][0], up=acc[qr][1], element-wise pairs ---
  int r16 = ((lane >> 4) & 3)*4;
#pragma unroll
  for (int qr=0;qr<2;qr++){
#pragma unroll
    for (int m=0;m<4;m++){
#pragma unroll
      for (int j=0;j<4;j++){
        int br = wm*128 + qr*64 + m*16 + r16 + j;
        if (row0 + br < n_e){
          size_t rowbase = (size_t)(ebase + row0 + br)*F_DIM + nt*128 + wn*32;
#pragma unroll
          for (int n=0;n<2;n++){
            float g = acc[qr][0][m][n][j];
            float u = acc[qr][1][m][n][j];
            float h = (g / (1.f + __expf(-g))) * u;
            hidden[rowbase + n*16 + (lane & 15)] = f2bf(h);
          }
        }
      }
    }
  }
}

// ---------------- phase 2: down-proj grouped GEMM + weighted combine --------
// A = hidden rows [128 x 64k], B = w2 [128 x 64k]; 2-barrier structure (proven)
__global__ __launch_bounds__(256) void k_ffn2(const unsigned short* __restrict__ hidden,
                                              const unsigned short* __restrict__ w2b,
                                              const int* __restrict__ ts128,
                                              const int* __restrict__ ts256,
                                              const int* __restrict__ counts,
                                              const int* __restrict__ entries,
                                              const float* __restrict__ topv,
                                              float* __restrict__ out){
  int flat = blockIdx.x;
  int nw = (flat & 7)*MAXT128 + (flat >> 3);  // 568 = 8*71 bijective
  int mt = nw % MAXT128;
  int nt = nw / MAXT128;
  if (mt >= ts128[E_NUM]) return;
  int e = 0;
  for (int i=E_NUM-1;i>=0;i--) if (mt >= ts128[i]){ e = i; break; }
  int n_e  = counts[e];
  int row0 = (mt - ts128[e])*128;
  int ebase = ts256[e]*256;

  __shared__ unsigned short lA[128*64];
  __shared__ unsigned short lB[128*64];

  int tid = threadIdx.x, lane = tid & 63, wid = tid >> 6;
  int wm = wid >> 1, wn = wid & 1;
  int seg = lane & 7, rsub = lane >> 3;

  const unsigned short* pA[4]; const unsigned short* pB[4];
  unsigned short *lAp[4], *lBp[4];
#pragma unroll
  for (int i=0;i<4;i++){
    int rb = (wid*4 + i)*8;
    int r  = rb + rsub;
    int sc = (seg ^ (r & 7)) * 8;
    pA[i]  = hidden + (size_t)(ebase + row0 + r)*F_DIM + sc;
    pB[i]  = w2b + ((size_t)e*H_DIM + nt*128 + r)*F_DIM + sc;
    lAp[i] = lA + rb*64;
    lBp[i] = lB + rb*64;
  }

  f32x4 acc[4][4];
#pragma unroll
  for (int m=0;m<4;m++)
#pragma unroll
    for (int n=0;n<4;n++) acc[m][n] = {0.f,0.f,0.f,0.f};

  int aoff[2][4], boff[2][4];
#pragma unroll
  for (int ks=0;ks<2;ks++){
    int kb = ks*64 + (lane >> 4)*16;
#pragma unroll
    for (int m=0;m<4;m++){
      int row = wm*64 + m*16 + (lane & 15);
      aoff[ks][m] = row*128 + (kb ^ ((row & 7) << 4));
    }
#pragma unroll
    for (int n=0;n<4;n++){
      int row = wn*64 + n*16 + (lane & 15);
      boff[ks][n] = row*128 + (kb ^ ((row & 7) << 4));
    }
  }

  for (int kk=0; kk<F_DIM; kk+=64){
#pragma unroll
    for (int i=0;i<4;i++)
      __builtin_amdgcn_global_load_lds(
        (const __attribute__((address_space(1))) unsigned int*)(pA[i] + kk),
        (__attribute__((address_space(3))) unsigned int*)(lAp[i]), 16, 0, 0);
#pragma unroll
    for (int i=0;i<4;i++)
      __builtin_amdgcn_global_load_lds(
        (const __attribute__((address_space(1))) unsigned int*)(pB[i] + kk),
        (__attribute__((address_space(3))) unsigned int*)(lBp[i]), 16, 0, 0);
    __syncthreads();
#pragma unroll
    for (int ks=0;ks<2;ks++){
      bf16x8 av[4], bv[4];
#pragma unroll
      for (int m=0;m<4;m++) av[m] = *(const bf16x8*)((const char*)lA + aoff[ks][m]);
#pragma unroll
      for (int n=0;n<4;n++) bv[n] = *(const bf16x8*)((const char*)lB + boff[ks][n]);
#pragma unroll
      for (int m=0;m<4;m++)
#pragma unroll
        for (int n=0;n<4;n++)
          acc[m][n] = __builtin_amdgcn_mfma_f32_16x16x32_bf16(av[m], bv[n], acc[m][n], 0,0,0);
    }
    __syncthreads();
  }

#pragma unroll
  for (int m=0;m<4;m++){
#pragma unroll
    for (int j=0;j<4;j++){
      int rit = wm*64 + m*16 + ((lane >> 4) & 3)*4 + j;
      int gr  = row0 + rit;
      if (gr < n_e){
        int packed = entries[ebase + gr];
        int t = packed >> 1;
        float w = topv[packed];
#pragma unroll
        for (int n=0;n<4;n++){
          int col = nt*128 + wn*64 + n*16 + (lane & 15);
          atomicAdd(&out[(size_t)t*H_DIM + col], w * acc[m][n][j]);
        }
      }
    }
  }
}

// ---------------------------------------------------------------------------
extern "C" void kernel_launch(void* const* d_in, const int* in_sizes, int n_in,
                              void* d_out, int out_size, void* d_ws, size_t ws_size,
                              hipStream_t stream){
  const float* x  = (const float*)d_in[0];
  const float* rw = (const float*)d_in[1];
  const float* w1 = (const float*)d_in[2];
  const float* w2 = (const float*)d_in[3];
  const float* w3 = (const float*)d_in[4];
  float* out = (float*)d_out;

  char* ws = (char*)d_ws;
  size_t off = 0;
  unsigned short* xb  = (unsigned short*)(ws + off); off += (size_t)T_TOK*H_DIM*2;
  unsigned short* w1b = (unsigned short*)(ws + off); off += (size_t)E_NUM*F_DIM*H_DIM*2;
  unsigned short* w3b = (unsigned short*)(ws + off); off += (size_t)E_NUM*F_DIM*H_DIM*2;
  unsigned short* w2b = (unsigned short*)(ws + off); off += (size_t)E_NUM*H_DIM*F_DIM*2;
  unsigned short* hidden = (unsigned short*)(ws + off); off += (size_t)MAXROWS*F_DIM*2;
  int*   counts  = (int*)(ws + off); off += 64;
  int*   ts128   = (int*)(ws + off); off += 64;
  int*   ts256   = (int*)(ws + off); off += 64;
  int*   cursors = (int*)(ws + off); off += 64;
  int*   topi    = (int*)(ws + off); off += (size_t)T_TOK*2*4;
  float* topv    = (float*)(ws + off); off += (size_t)T_TOK*2*4;
  int*   entries = (int*)(ws + off); off += (size_t)MAXROWS*4;

  hipFuncSetAttribute((const void*)k_ffn1,
                      hipFuncAttributeMaxDynamicSharedMemorySize, 131072);

  hipMemsetAsync(counts, 0, 32, stream);
  hipMemsetAsync(out, 0, (size_t)out_size*sizeof(float), stream);

  k_f2bf<<<2048, 256, 0, stream>>>(x,  xb,  T_TOK*H_DIM/4);
  k_f2bf<<<2048, 256, 0, stream>>>(w1, w1b, E_NUM*F_DIM*H_DIM/4);
  k_f2bf<<<2048, 256, 0, stream>>>(w3, w3b, E_NUM*F_DIM*H_DIM/4);
  k_f2bf<<<2048, 256, 0, stream>>>(w2, w2b, E_NUM*H_DIM*F_DIM/4);

  k_router<<<T_TOK, 64, 0, stream>>>(x, rw, counts, topi, topv);
  k_offsets<<<1, 64, 0, stream>>>(counts, ts128, ts256, cursors);
  k_fill<<<T_TOK/256, 256, 0, stream>>>(topi, ts256, cursors, entries);

  k_ffn1<<<MAXT256*16, 512, 131072, stream>>>(xb, w1b, w3b, ts256, counts, entries, hidden);
  k_ffn2<<<MAXT128*8, 256, 0, stream>>>(hidden, w2b, ts128, ts256, counts, entries, topv, out);
}

// Round 3
// 392.128 us; speedup vs baseline: 1.1993x; 1.0790x over previous
//
#include <hip/hip_runtime.h>
#include <hip/hip_bf16.h>
#include <cstdint>

#define T_TOK 4096
#define H_DIM 1024
#define F_DIM 2048
#define E_NUM 8
#define MAXT256 39
#define MAXROWS (MAXT256*256)   // 9984 padded entry rows

typedef __attribute__((ext_vector_type(8))) short bf16x8;
typedef __attribute__((ext_vector_type(4))) float f32x4;

__device__ __forceinline__ unsigned short f2bf(float f){
  union { float f; uint32_t u; } c; c.f = f;
  uint32_t u = c.u;
  uint32_t r = (u + 0x7fffu + ((u >> 16) & 1u)) >> 16;
  return (unsigned short)r;
}

// ---------------- weights fp32 -> bf16 (one kernel, 3 segments) -------------
__global__ __launch_bounds__(256) void k_wcvt(const float* __restrict__ w1,
                                              const float* __restrict__ w3,
                                              const float* __restrict__ w2,
                                              unsigned short* __restrict__ w1b,
                                              unsigned short* __restrict__ w3b,
                                              unsigned short* __restrict__ w2b){
  int seg = blockIdx.x >> 11;
  int b   = blockIdx.x & 2047;
  const float* s = seg==0 ? w1 : (seg==1 ? w3 : w2);
  unsigned short* d = seg==0 ? w1b : (seg==1 ? w3b : w2b);
  const int n4 = E_NUM*F_DIM*H_DIM/4;
  for (int i = b*256 + threadIdx.x; i < n4; i += 2048*256){
    float4 v = reinterpret_cast<const float4*>(s)[i];
    ushort4 o;
    o.x = f2bf(v.x); o.y = f2bf(v.y); o.z = f2bf(v.z); o.w = f2bf(v.w);
    reinterpret_cast<ushort4*>(d)[i] = o;
  }
}

// ------- router: fp64 logits, top-2, renorm weights; also emits xb bf16 -----
__global__ __launch_bounds__(64) void k_router(const float* __restrict__ x,
                                               const float* __restrict__ rw,
                                               int* __restrict__ counts,
                                               int* __restrict__ topi,
                                               float* __restrict__ topv,
                                               unsigned short* __restrict__ xb){
  int t = blockIdx.x;
  int lane = threadIdx.x;
  const float4* xr = reinterpret_cast<const float4*>(x + (size_t)t*H_DIM);
  float4 v[4];
#pragma unroll
  for (int i=0;i<4;i++) v[i] = xr[lane*4 + i];
  // bf16 copy of x (coalesced ushort4 stores)
  ushort4* xd = reinterpret_cast<ushort4*>(xb + (size_t)t*H_DIM);
#pragma unroll
  for (int i=0;i<4;i++){
    ushort4 o;
    o.x = f2bf(v[i].x); o.y = f2bf(v[i].y); o.z = f2bf(v[i].z); o.w = f2bf(v[i].w);
    xd[lane*4 + i] = o;
  }
  double acc[E_NUM];
#pragma unroll
  for (int e=0;e<E_NUM;e++){
    double a = 0.0;
    const float4* rwe = reinterpret_cast<const float4*>(rw + e*H_DIM);
#pragma unroll
    for (int i=0;i<4;i++){
      float4 r = rwe[lane*4 + i];
      a += (double)v[i].x*(double)r.x + (double)v[i].y*(double)r.y
         + (double)v[i].z*(double)r.z + (double)v[i].w*(double)r.w;
    }
    acc[e] = a;
  }
#pragma unroll
  for (int e=0;e<E_NUM;e++){
    double s = acc[e];
    for (int off=32; off>0; off>>=1) s += __shfl_xor(s, off, 64);
    acc[e] = s;
  }
  if (lane == 0){
    int i0 = 0; double v0 = acc[0];
    for (int e=1;e<E_NUM;e++) if (acc[e] > v0){ v0 = acc[e]; i0 = e; }
    int i1 = -1; double v1 = -1e300;
    for (int e=0;e<E_NUM;e++) if (e != i0 && acc[e] > v1){ v1 = acc[e]; i1 = e; }
    float w0 = 1.0f/(1.0f + expf((float)(v1 - v0)));  // softmax Z cancels in renorm
    topi[2*t] = i0; topi[2*t+1] = i1;
    topv[2*t] = w0; topv[2*t+1] = 1.0f - w0;
    atomicAdd(&counts[i0], 1); atomicAdd(&counts[i1], 1);
  }
}

// ---------------- per-expert padded tile offsets (256-granular) -------------
__global__ void k_offsets(const int* __restrict__ counts,
                          int* __restrict__ ts256, int* __restrict__ cursors){
  if (threadIdx.x == 0){
    int b = 0;
    for (int e=0;e<E_NUM;e++){ ts256[e] = b; b += (counts[e] + 255) >> 8; }
    ts256[E_NUM] = b;
  }
  if (threadIdx.x < E_NUM) cursors[threadIdx.x] = 0;
}

// ---------------- fill grouped entry lists ----------------------------------
__global__ __launch_bounds__(256) void k_fill(const int* __restrict__ topi,
                                              const int* __restrict__ ts256,
                                              int* __restrict__ cursors,
                                              int* __restrict__ entries){
  int t = blockIdx.x*256 + threadIdx.x;
  if (t >= T_TOK) return;
#pragma unroll
  for (int k=0;k<2;k++){
    int e = topi[2*t+k];
    int pos = atomicAdd(&cursors[e], 1);
    entries[ts256[e]*256 + pos] = 2*t + k;
  }
}

// ---------------- shared sync / staging macros ------------------------------
#define GLD(src, dst_us) __builtin_amdgcn_global_load_lds( \
  (const __attribute__((address_space(1))) unsigned int*)(src), \
  (__attribute__((address_space(3))) unsigned int*)(lds + (dst_us)), 16, 0, 0)

#define VMW(N) asm volatile("s_waitcnt vmcnt(" #N ")" ::: "memory")
#define BARS do{ __builtin_amdgcn_s_barrier(); __builtin_amdgcn_sched_barrier(0); }while(0)
#define MMGO do{ asm volatile("s_waitcnt lgkmcnt(0)" ::: "memory"); \
  __builtin_amdgcn_sched_barrier(0); __builtin_amdgcn_s_setprio(1); }while(0)
#define MMEND __builtin_amdgcn_s_setprio(0)

// ---------------- phase 1: 256x256 grouped GEMM + SiLU ----------------------
// C tile = 256 token-rows x 256 cols (even 32-blk = gate/w1, odd = up/w3,
// covering f-range nt*128..+128). A halves interleave rows by bit6.
// LDS: [dbuf 2][A0,A1,B0,B1][128x64 bf16] = 128 KiB dynamic.
// Waits: part consumed at tile T was issued at T-1 (4-5 phases earlier).

#define STG(X, s0, s1, dbS, kS) do{ \
  GLD((s0) + (kS)*64, (dbS)*32768 + (X)*8192 + dstb0); \
  GLD((s1) + (kS)*64, (dbS)*32768 + (X)*8192 + dstb1); }while(0)

#define LDA(db, QR) do{ const char* p_ = (const char*)lds + ((db)*4 + (QR))*16384; \
  _Pragma("unroll") for (int m_=0;m_<4;m_++) \
  _Pragma("unroll") for (int ks_=0;ks_<2;ks_++) \
    a[m_][ks_] = *(const bf16x8*)(p_ + aoff[m_][ks_]); }while(0)

#define LDB(db, QC, breg) do{ const char* p_ = (const char*)lds + ((db)*4 + 2 + (QC))*16384; \
  _Pragma("unroll") for (int n_=0;n_<2;n_++) \
  _Pragma("unroll") for (int ks_=0;ks_<2;ks_++) \
    breg[n_][ks_] = *(const bf16x8*)(p_ + boff[n_][ks_]); }while(0)

#define MM(QR, QC, breg) do{ \
  _Pragma("unroll") for (int m_=0;m_<4;m_++) \
  _Pragma("unroll") for (int n_=0;n_<2;n_++) \
  _Pragma("unroll") for (int ks_=0;ks_<2;ks_++) \
    acc[QR][QC][m_][n_] = __builtin_amdgcn_mfma_f32_16x16x32_bf16(a[m_][ks_], breg[n_][ks_], acc[QR][QC][m_][n_], 0,0,0); }while(0)

__global__ __launch_bounds__(512) void k_ffn1(const unsigned short* __restrict__ xb,
                                              const unsigned short* __restrict__ w1b,
                                              const unsigned short* __restrict__ w3b,
                                              const int* __restrict__ ts256,
                                              const int* __restrict__ counts,
                                              const int* __restrict__ entries,
                                              unsigned short* __restrict__ hidden){
  extern __shared__ unsigned short lds[];
  int flat = blockIdx.x;
  int nw = (flat & 7)*78 + (flat >> 3);     // 624 = 8*78 bijective XCD chunking
  int tile = nw % MAXT256;
  int nt   = nw / MAXT256;
  if (tile >= ts256[E_NUM]) return;
  int e = 0;
  for (int i=E_NUM-1;i>=0;i--) if (tile >= ts256[i]){ e = i; break; }
  int n_e  = counts[e];
  int row0 = (tile - ts256[e])*256;
  int ebase = ts256[e]*256;

  int tid = threadIdx.x, lane = tid & 63, wid = tid >> 6;
  int wm = wid >> 2, wn = wid & 3;          // 2 x 4 wave grid

  const unsigned short* sA[2][2];
  const unsigned short* sB[2][2];
#pragma unroll
  for (int h=0;h<2;h++){
#pragma unroll
    for (int i=0;i<2;i++){
      int idx = i*512 + tid;
      int r = idx >> 3, seg = idx & 7;
      int sc = (seg ^ (r & 7))*8;
      int br = ((r>>6)<<7) | (h<<6) | (r & 63);   // interleaved A halves (bit6)
      int rr = row0 + br; rr = rr < n_e ? rr : (n_e - 1);
      int tokr = entries[ebase + rr] >> 1;
      sA[h][i] = xb + (size_t)tokr*H_DIM + sc;
      const unsigned short* w = h ? w3b : w1b;    // B half0=w1(gate), half1=w3(up)
      sB[h][i] = w + ((size_t)e*F_DIM + nt*128 + r)*H_DIM + sc;
    }
  }
  int dstb0 = wid*512;
  int dstb1 = 4096 + wid*512;

  int aoff[4][2], boff[2][2];
#pragma unroll
  for (int m=0;m<4;m++){
    int ia = wm*64 + m*16 + (lane & 15);
#pragma unroll
    for (int ks=0;ks<2;ks++)
      aoff[m][ks] = ia*128 + ((ks*64 + (lane>>4)*16) ^ ((ia & 7) << 4));
  }
#pragma unroll
  for (int n=0;n<2;n++){
    int ib = wn*32 + n*16 + (lane & 15);
#pragma unroll
    for (int ks=0;ks<2;ks++)
      boff[n][ks] = ib*128 + ((ks*64 + (lane>>4)*16) ^ ((ib & 7) << 4));
  }

  f32x4 acc[2][2][4][2];
#pragma unroll
  for (int qr=0;qr<2;qr++)
#pragma unroll
  for (int qc=0;qc<2;qc++)
#pragma unroll
  for (int m=0;m<4;m++)
#pragma unroll
  for (int n=0;n<2;n++) acc[qr][qc][m][n] = {0.f,0.f,0.f,0.f};

  bf16x8 a[4][2], bA[2][2], bB[2][2];

  // prologue: stage tile 0 in ledger order A0,B0,B1,A1
  STG(0, sA[0][0], sA[0][1], 0, 0);
  STG(2, sB[0][0], sB[0][1], 0, 0);
  STG(3, sB[1][0], sB[1][1], 0, 0);
  STG(1, sA[1][0], sA[1][1], 0, 0);

  for (int T=0; T<15; ++T){
    int db = T & 1, dbS = db ^ 1, kS = T + 1;
    // q0: needs A0,B0 (issued T-1 q0, 4 phases ago)
    VMW(4); BARS;
    LDA(db,0); LDB(db,0,bA);
    STG(0, sA[0][0], sA[0][1], dbS, kS);
    STG(2, sB[0][0], sB[0][1], dbS, kS);
    MMGO; MM(0,0,bA); MMEND;
    // q1: needs B1 (issued T-1 q1, 4 phases ago)
    VMW(6); BARS;
    LDB(db,1,bB);
    STG(3, sB[1][0], sB[1][1], dbS, kS);
    STG(1, sA[1][0], sA[1][1], dbS, kS);
    MMGO; MM(0,1,bB); MMEND;
    // q2+q3: needs A1 (issued T-1 q1, 5 phases ago); 32 MFMA
    VMW(8); BARS;
    LDA(db,1);
    MMGO; MM(1,0,bA); MM(1,1,bB); MMEND;
  }
  // epilogue tile 15 (db=1), no staging: drain 4 -> 2 -> 0
  VMW(4); BARS; LDA(1,0); LDB(1,0,bA); MMGO; MM(0,0,bA); MMEND;
  VMW(2); BARS; LDB(1,1,bB);           MMGO; MM(0,1,bB); MMEND;
  VMW(0); BARS; LDA(1,1);              MMGO; MM(1,0,bA); MM(1,1,bB); MMEND;

  // SiLU epilogue: gate=acc[qr][0], up=acc[qr][1]
  int r16 = ((lane >> 4) & 3)*4;
#pragma unroll
  for (int qr=0;qr<2;qr++){
#pragma unroll
    for (int m=0;m<4;m++){
#pragma unroll
      for (int j=0;j<4;j++){
        int br = wm*128 + qr*64 + m*16 + r16 + j;
        if (row0 + br < n_e){
          size_t rowbase = (size_t)(ebase + row0 + br)*F_DIM + nt*128 + wn*32;
#pragma unroll
          for (int n=0;n<2;n++){
            float g = acc[qr][0][m][n][j];
            float u = acc[qr][1][m][n][j];
            float h = (g / (1.f + __expf(-g))) * u;
            hidden[rowbase + n*16 + (lane & 15)] = f2bf(h);
          }
        }
      }
    }
  }
}

// ---------------- phase 2: 256x128 grouped GEMM + weighted combine ----------
// A = 256 hidden rows (bit6-interleaved halves), B = 128 w2 rows.
// Triple-buffered LDS (3 x 48 KiB), staged 2 tiles ahead (4-phase distance).
// Grid 312 = 8 XCD x 39: each XCD owns one nt -> its 4 MB w2 panel = its L2.

#define STG2(P, s0, s1, slot, kS) do{ \
  GLD((s0) + (kS)*64, (slot)*24576 + (P)*8192 + dstb0); \
  GLD((s1) + (kS)*64, (slot)*24576 + (P)*8192 + dstb1); }while(0)

#define LDA2(slot, QR) do{ const char* p_ = (const char*)lds + (slot)*49152 + (QR)*16384; \
  _Pragma("unroll") for (int m_=0;m_<4;m_++) \
  _Pragma("unroll") for (int ks_=0;ks_<2;ks_++) \
    a[m_][ks_] = *(const bf16x8*)(p_ + aoff[m_][ks_]); }while(0)

#define LDB2(slot) do{ const char* p_ = (const char*)lds + (slot)*49152 + 32768; \
  _Pragma("unroll") for (int n_=0;n_<2;n_++) \
  _Pragma("unroll") for (int ks_=0;ks_<2;ks_++) \
    b[n_][ks_] = *(const bf16x8*)(p_ + boff[n_][ks_]); }while(0)

#define MMF(QR) do{ \
  _Pragma("unroll") for (int m_=0;m_<4;m_++) \
  _Pragma("unroll") for (int n_=0;n_<2;n_++) \
  _Pragma("unroll") for (int ks_=0;ks_<2;ks_++) \
    acc[QR][m_][n_] = __builtin_amdgcn_mfma_f32_16x16x32_bf16(a[m_][ks_], b[n_][ks_], acc[QR][m_][n_], 0,0,0); }while(0)

__global__ __launch_bounds__(512) void k_ffn2(const unsigned short* __restrict__ hidden,
                                              const unsigned short* __restrict__ w2b,
                                              const int* __restrict__ ts256,
                                              const int* __restrict__ counts,
                                              const int* __restrict__ entries,
                                              const float* __restrict__ topv,
                                              float* __restrict__ out){
  extern __shared__ unsigned short lds[];   // 3 * 24576 ushorts = 144 KiB
  int flat = blockIdx.x;
  int nw = (flat & 7)*MAXT256 + (flat >> 3);  // 312 = 8*39 bijective
  int tile = nw % MAXT256;
  int nt   = nw / MAXT256;                    // one nt per XCD
  if (tile >= ts256[E_NUM]) return;
  int e = 0;
  for (int i=E_NUM-1;i>=0;i--) if (tile >= ts256[i]){ e = i; break; }
  int n_e  = counts[e];
  int row0 = (tile - ts256[e])*256;
  int ebase = ts256[e]*256;

  int tid = threadIdx.x, lane = tid & 63, wid = tid >> 6;
  int wm = wid >> 2, wn = wid & 3;

  const unsigned short* sA[2][2];
  const unsigned short* sB[2];
#pragma unroll
  for (int h=0;h<2;h++){
#pragma unroll
    for (int i=0;i<2;i++){
      int idx = i*512 + tid;
      int r = idx >> 3, seg = idx & 7;
      int sc = (seg ^ (r & 7))*8;
      int br = ((r>>6)<<7) | (h<<6) | (r & 63);
      sA[h][i] = hidden + (size_t)(ebase + row0 + br)*F_DIM + sc;  // padded rows: benign stale data, outputs discarded
    }
  }
#pragma unroll
  for (int i=0;i<2;i++){
    int idx = i*512 + tid;
    int r = idx >> 3, seg = idx & 7;
    int sc = (seg ^ (r & 7))*8;
    sB[i] = w2b + ((size_t)e*H_DIM + nt*128 + r)*F_DIM + sc;
  }
  int dstb0 = wid*512;
  int dstb1 = 4096 + wid*512;

  int aoff[4][2], boff[2][2];
#pragma unroll
  for (int m=0;m<4;m++){
    int ia = wm*64 + m*16 + (lane & 15);
#pragma unroll
    for (int ks=0;ks<2;ks++)
      aoff[m][ks] = ia*128 + ((ks*64 + (lane>>4)*16) ^ ((ia & 7) << 4));
  }
#pragma unroll
  for (int n=0;n<2;n++){
    int ib = wn*32 + n*16 + (lane & 15);
#pragma unroll
    for (int ks=0;ks<2;ks++)
      boff[n][ks] = ib*128 + ((ks*64 + (lane>>4)*16) ^ ((ib & 7) << 4));
  }

  f32x4 acc[2][4][2];
#pragma unroll
  for (int qr=0;qr<2;qr++)
#pragma unroll
  for (int m=0;m<4;m++)
#pragma unroll
  for (int n=0;n<2;n++) acc[qr][m][n] = {0.f,0.f,0.f,0.f};

  bf16x8 a[4][2], b[2][2];

  // prologue: stage tiles 0 and 1 in ledger order (A0,B,A1) each
  STG2(0, sA[0][0], sA[0][1], 0, 0);
  STG2(2, sB[0],    sB[1],    0, 0);
  STG2(1, sA[1][0], sA[1][1], 0, 0);
  STG2(0, sA[0][0], sA[0][1], 1, 1);
  STG2(2, sB[0],    sB[1],    1, 1);
  STG2(1, sA[1][0], sA[1][1], 1, 1);

  int cur = 0, n2 = 2;
  for (int T=0; T<30; ++T){
    // q0: needs A0(T),B(T) (issued T-2 q0, 4 phases ago)
    VMW(8); BARS;
    LDA2(cur,0); LDB2(cur);
    STG2(0, sA[0][0], sA[0][1], n2, T+2);
    STG2(2, sB[0],    sB[1],    n2, T+2);
    MMGO; MMF(0); MMEND;
    // q1: needs A1(T) (issued T-2 q1, 4 phases ago)
    VMW(10); BARS;
    LDA2(cur,1);
    STG2(1, sA[1][0], sA[1][1], n2, T+2);
    MMGO; MMF(1); MMEND;
    cur = cur==2 ? 0 : cur+1;
    n2  = n2==2 ? 0 : n2+1;
  }
  // T=30 (cur=0): no staging
  VMW(8); BARS; LDA2(cur,0); LDB2(cur); MMGO; MMF(0); MMEND;
  VMW(6); BARS; LDA2(cur,1);            MMGO; MMF(1); MMEND;
  cur = cur==2 ? 0 : cur+1;
  // T=31
  VMW(2); BARS; LDA2(cur,0); LDB2(cur); MMGO; MMF(0); MMEND;
  VMW(0); BARS; LDA2(cur,1);            MMGO; MMF(1); MMEND;

  // weighted combine via fp32 atomics (each out elem receives exactly 2 adds)
  int r16 = ((lane >> 4) & 3)*4;
#pragma unroll
  for (int qr=0;qr<2;qr++){
#pragma unroll
    for (int m=0;m<4;m++){
#pragma unroll
      for (int j=0;j<4;j++){
        int gr = row0 + wm*128 + qr*64 + m*16 + r16 + j;
        if (gr < n_e){
          int packed = entries[ebase + gr];
          int t = packed >> 1;
          float w = topv[packed];
#pragma unroll
          for (int n=0;n<2;n++){
            int col = nt*128 + wn*32 + n*16 + (lane & 15);
            atomicAdd(&out[(size_t)t*H_DIM + col], w * acc[qr][m][n][j]);
          }
        }
      }
    }
  }
}

// ---------------------------------------------------------------------------
extern "C" void kernel_launch(void* const* d_in, const int* in_sizes, int n_in,
                              void* d_out, int out_size, void* d_ws, size_t ws_size,
                              hipStream_t stream){
  const float* x  = (const float*)d_in[0];
  const float* rw = (const float*)d_in[1];
  const float* w1 = (const float*)d_in[2];
  const float* w2 = (const float*)d_in[3];
  const float* w3 = (const float*)d_in[4];
  float* out = (float*)d_out;

  char* ws = (char*)d_ws;
  size_t off = 0;
  unsigned short* xb  = (unsigned short*)(ws + off); off += (size_t)T_TOK*H_DIM*2;
  unsigned short* w1b = (unsigned short*)(ws + off); off += (size_t)E_NUM*F_DIM*H_DIM*2;
  unsigned short* w3b = (unsigned short*)(ws + off); off += (size_t)E_NUM*F_DIM*H_DIM*2;
  unsigned short* w2b = (unsigned short*)(ws + off); off += (size_t)E_NUM*H_DIM*F_DIM*2;
  unsigned short* hidden = (unsigned short*)(ws + off); off += (size_t)MAXROWS*F_DIM*2;
  int*   counts  = (int*)(ws + off); off += 64;
  int*   ts256   = (int*)(ws + off); off += 64;
  int*   cursors = (int*)(ws + off); off += 64;
  int*   topi    = (int*)(ws + off); off += (size_t)T_TOK*2*4;
  float* topv    = (float*)(ws + off); off += (size_t)T_TOK*2*4;
  int*   entries = (int*)(ws + off); off += (size_t)MAXROWS*4;

  hipFuncSetAttribute((const void*)k_ffn1,
                      hipFuncAttributeMaxDynamicSharedMemorySize, 131072);
  hipFuncSetAttribute((const void*)k_ffn2,
                      hipFuncAttributeMaxDynamicSharedMemorySize, 147456);

  hipMemsetAsync(counts, 0, 32, stream);
  hipMemsetAsync(out, 0, (size_t)out_size*sizeof(float), stream);

  k_router<<<T_TOK, 64, 0, stream>>>(x, rw, counts, topi, topv, xb);
  k_offsets<<<1, 64, 0, stream>>>(counts, ts256, cursors);
  k_fill<<<T_TOK/256, 256, 0, stream>>>(topi, ts256, cursors, entries);
  k_wcvt<<<3*2048, 256, 0, stream>>>(w1, w3, w2, w1b, w3b, w2b);

  k_ffn1<<<MAXT256*16, 512, 131072, stream>>>(xb, w1b, w3b, ts256, counts, entries, hidden);
  k_ffn2<<<MAXT256*8, 512, 147456, stream>>>(hidden, w2b, ts256, counts, entries, topv, out);
}

// Round 4
// 312.298 us; speedup vs baseline: 1.5059x; 1.2556x over previous
//
#include <hip/hip_runtime.h>
#include <hip/hip_bf16.h>
#include <cstdint>

#define T_TOK 4096
#define H_DIM 1024
#define F_DIM 2048
#define E_NUM 8
#define MAXT256 39
#define MAXROWS (MAXT256*256)   // 9984 padded entry rows

typedef __attribute__((ext_vector_type(8))) short bf16x8;
typedef __attribute__((ext_vector_type(4))) float f32x4;

__device__ __forceinline__ unsigned short f2bf(float f){
  union { float f; uint32_t u; } c; c.f = f;
  uint32_t u = c.u;
  uint32_t r = (u + 0x7fffu + ((u >> 16) & 1u)) >> 16;
  return (unsigned short)r;
}

// ---------------- weights fp32 -> bf16 (one kernel, 3 segments) -------------
__global__ __launch_bounds__(256) void k_wcvt(const float* __restrict__ w1,
                                              const float* __restrict__ w3,
                                              const float* __restrict__ w2,
                                              unsigned short* __restrict__ w1b,
                                              unsigned short* __restrict__ w3b,
                                              unsigned short* __restrict__ w2b){
  int seg = blockIdx.x >> 11;
  int b   = blockIdx.x & 2047;
  const float* s = seg==0 ? w1 : (seg==1 ? w3 : w2);
  unsigned short* d = seg==0 ? w1b : (seg==1 ? w3b : w2b);
  const int n4 = E_NUM*F_DIM*H_DIM/4;
  for (int i = b*256 + threadIdx.x; i < n4; i += 2048*256){
    float4 v = reinterpret_cast<const float4*>(s)[i];
    ushort4 o;
    o.x = f2bf(v.x); o.y = f2bf(v.y); o.z = f2bf(v.z); o.w = f2bf(v.w);
    reinterpret_cast<ushort4*>(d)[i] = o;
  }
}

// ------- router: 32 tokens/block, 8 lanes/token, rw staged in LDS -----------
// fp64 accumulation (exact top-2 selection), 3-level 8-lane shuffle reduce,
// per-block LDS histogram -> 8 global atomics. Also emits bf16 copy of x.
__global__ __launch_bounds__(256) void k_router(const float* __restrict__ x,
                                               const float* __restrict__ rw,
                                               int* __restrict__ counts,
                                               int* __restrict__ topi,
                                               float* __restrict__ topv,
                                               unsigned short* __restrict__ xb){
  __shared__ float lrw[E_NUM][8][132];   // 132 = 128 + 4 pad: 4-bank shift/chunk
  __shared__ int hist[E_NUM];
  int tid = threadIdx.x;
  if (tid < E_NUM) hist[tid] = 0;
  for (int i = tid; i < E_NUM*H_DIM/4; i += 256){
    int idx = i*4;
    int e = idx >> 10, rem = idx & 1023, c = rem >> 7, j = rem & 127;
    float4 v = reinterpret_cast<const float4*>(rw)[i];
    *reinterpret_cast<float4*>(&lrw[e][c][j]) = v;
  }
  __syncthreads();

  int t = blockIdx.x*32 + (tid >> 3);
  int c = tid & 7;
  const float4* xr = reinterpret_cast<const float4*>(x + (size_t)t*H_DIM + c*128);
  ushort4* xw = reinterpret_cast<ushort4*>(xb + (size_t)t*H_DIM + c*128);
  double acc[E_NUM];
#pragma unroll
  for (int e=0;e<E_NUM;e++) acc[e] = 0.0;
  for (int j4=0; j4<32; ++j4){
    float4 v = xr[j4];
    ushort4 o;
    o.x = f2bf(v.x); o.y = f2bf(v.y); o.z = f2bf(v.z); o.w = f2bf(v.w);
    xw[j4] = o;
#pragma unroll
    for (int e=0;e<E_NUM;e++){
      float4 r = *reinterpret_cast<const float4*>(&lrw[e][c][j4*4]);
      acc[e] += (double)v.x*(double)r.x + (double)v.y*(double)r.y
              + (double)v.z*(double)r.z + (double)v.w*(double)r.w;
    }
  }
#pragma unroll
  for (int e=0;e<E_NUM;e++){
    double s = acc[e];
    s += __shfl_xor(s, 1, 64);
    s += __shfl_xor(s, 2, 64);
    s += __shfl_xor(s, 4, 64);
    acc[e] = s;
  }
  if (c == 0){
    int i0 = 0; double v0 = acc[0];
    for (int e=1;e<E_NUM;e++) if (acc[e] > v0){ v0 = acc[e]; i0 = e; }
    int i1 = -1; double v1 = -1e300;
    for (int e=0;e<E_NUM;e++) if (e != i0 && acc[e] > v1){ v1 = acc[e]; i1 = e; }
    float w0 = 1.0f/(1.0f + expf((float)(v1 - v0)));  // softmax Z cancels in renorm
    topi[2*t] = i0; topi[2*t+1] = i1;
    topv[2*t] = w0; topv[2*t+1] = 1.0f - w0;
    atomicAdd(&hist[i0], 1); atomicAdd(&hist[i1], 1);
  }
  __syncthreads();
  if (tid < E_NUM && hist[tid]) atomicAdd(&counts[tid], hist[tid]);
}

// ---------------- per-expert padded tile offsets (256-granular) -------------
__global__ void k_offsets(const int* __restrict__ counts,
                          int* __restrict__ ts256, int* __restrict__ cursors){
  if (threadIdx.x == 0){
    int b = 0;
    for (int e=0;e<E_NUM;e++){ ts256[e] = b; b += (counts[e] + 255) >> 8; }
    ts256[E_NUM] = b;
  }
  if (threadIdx.x < E_NUM) cursors[threadIdx.x] = 0;
}

// ---------------- fill grouped entry lists ----------------------------------
__global__ __launch_bounds__(256) void k_fill(const int* __restrict__ topi,
                                              const int* __restrict__ ts256,
                                              int* __restrict__ cursors,
                                              int* __restrict__ entries){
  int t = blockIdx.x*256 + threadIdx.x;
  if (t >= T_TOK) return;
#pragma unroll
  for (int k=0;k<2;k++){
    int e = topi[2*t+k];
    int pos = atomicAdd(&cursors[e], 1);
    entries[ts256[e]*256 + pos] = 2*t + k;
  }
}

// ---------------- shared sync / staging macros ------------------------------
#define GLD(src, dst_us) __builtin_amdgcn_global_load_lds( \
  (const __attribute__((address_space(1))) unsigned int*)(src), \
  (__attribute__((address_space(3))) unsigned int*)(lds + (dst_us)), 16, 0, 0)

#define VMW(N) asm volatile("s_waitcnt vmcnt(" #N ")" ::: "memory")
#define BARS do{ __builtin_amdgcn_s_barrier(); __builtin_amdgcn_sched_barrier(0); }while(0)
#define MMGO do{ asm volatile("s_waitcnt lgkmcnt(0)" ::: "memory"); \
  __builtin_amdgcn_sched_barrier(0); __builtin_amdgcn_s_setprio(1); }while(0)
#define MMEND __builtin_amdgcn_s_setprio(0)

// ---------------- phase 1: 256x256 grouped GEMM + SiLU ----------------------
// C tile = 256 token-rows x 256 cols (even 32-blk = gate/w1, odd = up/w3,
// covering f-range nt*128..+128). A halves interleave rows by bit6.
// LDS: [dbuf 2][A0,A1,B0,B1][128x64 bf16] = 128 KiB dynamic.
// Waits: part consumed at tile T was issued at T-1 (4-5 phases earlier).

#define STG(X, s0, s1, dbS, kS) do{ \
  GLD((s0) + (kS)*64, (dbS)*32768 + (X)*8192 + dstb0); \
  GLD((s1) + (kS)*64, (dbS)*32768 + (X)*8192 + dstb1); }while(0)

#define LDA(db, QR) do{ const char* p_ = (const char*)lds + ((db)*4 + (QR))*16384; \
  _Pragma("unroll") for (int m_=0;m_<4;m_++) \
  _Pragma("unroll") for (int ks_=0;ks_<2;ks_++) \
    a[m_][ks_] = *(const bf16x8*)(p_ + aoff[m_][ks_]); }while(0)

#define LDB(db, QC, breg) do{ const char* p_ = (const char*)lds + ((db)*4 + 2 + (QC))*16384; \
  _Pragma("unroll") for (int n_=0;n_<2;n_++) \
  _Pragma("unroll") for (int ks_=0;ks_<2;ks_++) \
    breg[n_][ks_] = *(const bf16x8*)(p_ + boff[n_][ks_]); }while(0)

#define MM(QR, QC, breg) do{ \
  _Pragma("unroll") for (int m_=0;m_<4;m_++) \
  _Pragma("unroll") for (int n_=0;n_<2;n_++) \
  _Pragma("unroll") for (int ks_=0;ks_<2;ks_++) \
    acc[QR][QC][m_][n_] = __builtin_amdgcn_mfma_f32_16x16x32_bf16(a[m_][ks_], breg[n_][ks_], acc[QR][QC][m_][n_], 0,0,0); }while(0)

__global__ __launch_bounds__(512) void k_ffn1(const unsigned short* __restrict__ xb,
                                              const unsigned short* __restrict__ w1b,
                                              const unsigned short* __restrict__ w3b,
                                              const int* __restrict__ ts256,
                                              const int* __restrict__ counts,
                                              const int* __restrict__ entries,
                                              unsigned short* __restrict__ hidden){
  extern __shared__ unsigned short lds[];
  int flat = blockIdx.x;
  int nw = (flat & 7)*78 + (flat >> 3);     // 624 = 8*78 bijective XCD chunking
  int tile = nw % MAXT256;
  int nt   = nw / MAXT256;
  if (tile >= ts256[E_NUM]) return;
  int e = 0;
  for (int i=E_NUM-1;i>=0;i--) if (tile >= ts256[i]){ e = i; break; }
  int n_e  = counts[e];
  int row0 = (tile - ts256[e])*256;
  int ebase = ts256[e]*256;

  int tid = threadIdx.x, lane = tid & 63, wid = tid >> 6;
  int wm = wid >> 2, wn = wid & 3;          // 2 x 4 wave grid

  const unsigned short* sA[2][2];
  const unsigned short* sB[2][2];
#pragma unroll
  for (int h=0;h<2;h++){
#pragma unroll
    for (int i=0;i<2;i++){
      int idx = i*512 + tid;
      int r = idx >> 3, seg = idx & 7;
      int sc = (seg ^ (r & 7))*8;
      int br = ((r>>6)<<7) | (h<<6) | (r & 63);   // interleaved A halves (bit6)
      int rr = row0 + br; rr = rr < n_e ? rr : (n_e - 1);
      int tokr = entries[ebase + rr] >> 1;
      sA[h][i] = xb + (size_t)tokr*H_DIM + sc;
      const unsigned short* w = h ? w3b : w1b;    // B half0=w1(gate), half1=w3(up)
      sB[h][i] = w + ((size_t)e*F_DIM + nt*128 + r)*H_DIM + sc;
    }
  }
  int dstb0 = wid*512;
  int dstb1 = 4096 + wid*512;

  int aoff[4][2], boff[2][2];
#pragma unroll
  for (int m=0;m<4;m++){
    int ia = wm*64 + m*16 + (lane & 15);
#pragma unroll
    for (int ks=0;ks<2;ks++)
      aoff[m][ks] = ia*128 + ((ks*64 + (lane>>4)*16) ^ ((ia & 7) << 4));
  }
#pragma unroll
  for (int n=0;n<2;n++){
    int ib = wn*32 + n*16 + (lane & 15);
#pragma unroll
    for (int ks=0;ks<2;ks++)
      boff[n][ks] = ib*128 + ((ks*64 + (lane>>4)*16) ^ ((ib & 7) << 4));
  }

  f32x4 acc[2][2][4][2];
#pragma unroll
  for (int qr=0;qr<2;qr++)
#pragma unroll
  for (int qc=0;qc<2;qc++)
#pragma unroll
  for (int m=0;m<4;m++)
#pragma unroll
  for (int n=0;n<2;n++) acc[qr][qc][m][n] = {0.f,0.f,0.f,0.f};

  bf16x8 a[4][2], bA[2][2], bB[2][2];

  // prologue: stage tile 0 in ledger order A0,B0,B1,A1
  STG(0, sA[0][0], sA[0][1], 0, 0);
  STG(2, sB[0][0], sB[0][1], 0, 0);
  STG(3, sB[1][0], sB[1][1], 0, 0);
  STG(1, sA[1][0], sA[1][1], 0, 0);

  for (int T=0; T<15; ++T){
    int db = T & 1, dbS = db ^ 1, kS = T + 1;
    // q0: needs A0,B0 (issued T-1 q0, 4 phases ago)
    VMW(4); BARS;
    LDA(db,0); LDB(db,0,bA);
    STG(0, sA[0][0], sA[0][1], dbS, kS);
    STG(2, sB[0][0], sB[0][1], dbS, kS);
    MMGO; MM(0,0,bA); MMEND;
    // q1: needs B1 (issued T-1 q1, 4 phases ago)
    VMW(6); BARS;
    LDB(db,1,bB);
    STG(3, sB[1][0], sB[1][1], dbS, kS);
    STG(1, sA[1][0], sA[1][1], dbS, kS);
    MMGO; MM(0,1,bB); MMEND;
    // q2+q3: needs A1 (issued T-1 q1, 5 phases ago); 32 MFMA
    VMW(8); BARS;
    LDA(db,1);
    MMGO; MM(1,0,bA); MM(1,1,bB); MMEND;
  }
  // epilogue tile 15 (db=1), no staging: drain 4 -> 2 -> 0
  VMW(4); BARS; LDA(1,0); LDB(1,0,bA); MMGO; MM(0,0,bA); MMEND;
  VMW(2); BARS; LDB(1,1,bB);           MMGO; MM(0,1,bB); MMEND;
  VMW(0); BARS; LDA(1,1);              MMGO; MM(1,0,bA); MM(1,1,bB); MMEND;

  // SiLU epilogue: gate=acc[qr][0], up=acc[qr][1]
  int r16 = ((lane >> 4) & 3)*4;
#pragma unroll
  for (int qr=0;qr<2;qr++){
#pragma unroll
    for (int m=0;m<4;m++){
#pragma unroll
      for (int j=0;j<4;j++){
        int br = wm*128 + qr*64 + m*16 + r16 + j;
        if (row0 + br < n_e){
          size_t rowbase = (size_t)(ebase + row0 + br)*F_DIM + nt*128 + wn*32;
#pragma unroll
          for (int n=0;n<2;n++){
            float g = acc[qr][0][m][n][j];
            float u = acc[qr][1][m][n][j];
            float h = (g / (1.f + __expf(-g))) * u;
            hidden[rowbase + n*16 + (lane & 15)] = f2bf(h);
          }
        }
      }
    }
  }
}

// ---------------- phase 2: 256x128 grouped GEMM + weighted combine ----------
// A = 256 hidden rows (bit6-interleaved halves), B = 128 w2 rows.
// Triple-buffered LDS (3 x 48 KiB), staged 2 tiles ahead (4-phase distance).
// Grid 312 = 8 XCD x 39: each XCD owns one nt -> its 4 MB w2 panel = its L2.

#define STG2(P, s0, s1, slot, kS) do{ \
  GLD((s0) + (kS)*64, (slot)*24576 + (P)*8192 + dstb0); \
  GLD((s1) + (kS)*64, (slot)*24576 + (P)*8192 + dstb1); }while(0)

#define LDA2(slot, QR) do{ const char* p_ = (const char*)lds + (slot)*49152 + (QR)*16384; \
  _Pragma("unroll") for (int m_=0;m_<4;m_++) \
  _Pragma("unroll") for (int ks_=0;ks_<2;ks_++) \
    a[m_][ks_] = *(const bf16x8*)(p_ + aoff[m_][ks_]); }while(0)

#define LDB2(slot) do{ const char* p_ = (const char*)lds + (slot)*49152 + 32768; \
  _Pragma("unroll") for (int n_=0;n_<2;n_++) \
  _Pragma("unroll") for (int ks_=0;ks_<2;ks_++) \
    b[n_][ks_] = *(const bf16x8*)(p_ + boff[n_][ks_]); }while(0)

#define MMF(QR) do{ \
  _Pragma("unroll") for (int m_=0;m_<4;m_++) \
  _Pragma("unroll") for (int n_=0;n_<2;n_++) \
  _Pragma("unroll") for (int ks_=0;ks_<2;ks_++) \
    acc[QR][m_][n_] = __builtin_amdgcn_mfma_f32_16x16x32_bf16(a[m_][ks_], b[n_][ks_], acc[QR][m_][n_], 0,0,0); }while(0)

__global__ __launch_bounds__(512) void k_ffn2(const unsigned short* __restrict__ hidden,
                                              const unsigned short* __restrict__ w2b,
                                              const int* __restrict__ ts256,
                                              const int* __restrict__ counts,
                                              const int* __restrict__ entries,
                                              const float* __restrict__ topv,
                                              float* __restrict__ out){
  extern __shared__ unsigned short lds[];   // 3 * 24576 ushorts = 144 KiB
  int flat = blockIdx.x;
  int nw = (flat & 7)*MAXT256 + (flat >> 3);  // 312 = 8*39 bijective
  int tile = nw % MAXT256;
  int nt   = nw / MAXT256;                    // one nt per XCD
  if (tile >= ts256[E_NUM]) return;
  int e = 0;
  for (int i=E_NUM-1;i>=0;i--) if (tile >= ts256[i]){ e = i; break; }
  int n_e  = counts[e];
  int row0 = (tile - ts256[e])*256;
  int ebase = ts256[e]*256;

  int tid = threadIdx.x, lane = tid & 63, wid = tid >> 6;
  int wm = wid >> 2, wn = wid & 3;

  const unsigned short* sA[2][2];
  const unsigned short* sB[2];
#pragma unroll
  for (int h=0;h<2;h++){
#pragma unroll
    for (int i=0;i<2;i++){
      int idx = i*512 + tid;
      int r = idx >> 3, seg = idx & 7;
      int sc = (seg ^ (r & 7))*8;
      int br = ((r>>6)<<7) | (h<<6) | (r & 63);
      sA[h][i] = hidden + (size_t)(ebase + row0 + br)*F_DIM + sc;  // padded rows: benign stale data, outputs discarded
    }
  }
#pragma unroll
  for (int i=0;i<2;i++){
    int idx = i*512 + tid;
    int r = idx >> 3, seg = idx & 7;
    int sc = (seg ^ (r & 7))*8;
    sB[i] = w2b + ((size_t)e*H_DIM + nt*128 + r)*F_DIM + sc;
  }
  int dstb0 = wid*512;
  int dstb1 = 4096 + wid*512;

  int aoff[4][2], boff[2][2];
#pragma unroll
  for (int m=0;m<4;m++){
    int ia = wm*64 + m*16 + (lane & 15);
#pragma unroll
    for (int ks=0;ks<2;ks++)
      aoff[m][ks] = ia*128 + ((ks*64 + (lane>>4)*16) ^ ((ia & 7) << 4));
  }
#pragma unroll
  for (int n=0;n<2;n++){
    int ib = wn*32 + n*16 + (lane & 15);
#pragma unroll
    for (int ks=0;ks<2;ks++)
      boff[n][ks] = ib*128 + ((ks*64 + (lane>>4)*16) ^ ((ib & 7) << 4));
  }

  f32x4 acc[2][4][2];
#pragma unroll
  for (int qr=0;qr<2;qr++)
#pragma unroll
  for (int m=0;m<4;m++)
#pragma unroll
  for (int n=0;n<2;n++) acc[qr][m][n] = {0.f,0.f,0.f,0.f};

  bf16x8 a[4][2], b[2][2];

  // prologue: stage tiles 0 and 1 in ledger order (A0,B,A1) each
  STG2(0, sA[0][0], sA[0][1], 0, 0);
  STG2(2, sB[0],    sB[1],    0, 0);
  STG2(1, sA[1][0], sA[1][1], 0, 0);
  STG2(0, sA[0][0], sA[0][1], 1, 1);
  STG2(2, sB[0],    sB[1],    1, 1);
  STG2(1, sA[1][0], sA[1][1], 1, 1);

  int cur = 0, n2 = 2;
  for (int T=0; T<30; ++T){
    // q0: needs A0(T),B(T) (issued T-2 q0, 4 phases ago)
    VMW(8); BARS;
    LDA2(cur,0); LDB2(cur);
    STG2(0, sA[0][0], sA[0][1], n2, T+2);
    STG2(2, sB[0],    sB[1],    n2, T+2);
    MMGO; MMF(0); MMEND;
    // q1: needs A1(T) (issued T-2 q1, 4 phases ago)
    VMW(10); BARS;
    LDA2(cur,1);
    STG2(1, sA[1][0], sA[1][1], n2, T+2);
    MMGO; MMF(1); MMEND;
    cur = cur==2 ? 0 : cur+1;
    n2  = n2==2 ? 0 : n2+1;
  }
  // T=30 (cur=0): no staging
  VMW(8); BARS; LDA2(cur,0); LDB2(cur); MMGO; MMF(0); MMEND;
  VMW(6); BARS; LDA2(cur,1);            MMGO; MMF(1); MMEND;
  cur = cur==2 ? 0 : cur+1;
  // T=31
  VMW(2); BARS; LDA2(cur,0); LDB2(cur); MMGO; MMF(0); MMEND;
  VMW(0); BARS; LDA2(cur,1);            MMGO; MMF(1); MMEND;

  // weighted combine via fp32 atomics (each out elem receives exactly 2 adds)
  int r16 = ((lane >> 4) & 3)*4;
#pragma unroll
  for (int qr=0;qr<2;qr++){
#pragma unroll
    for (int m=0;m<4;m++){
#pragma unroll
      for (int j=0;j<4;j++){
        int gr = row0 + wm*128 + qr*64 + m*16 + r16 + j;
        if (gr < n_e){
          int packed = entries[ebase + gr];
          int t = packed >> 1;
          float w = topv[packed];
#pragma unroll
          for (int n=0;n<2;n++){
            int col = nt*128 + wn*32 + n*16 + (lane & 15);
            atomicAdd(&out[(size_t)t*H_DIM + col], w * acc[qr][m][n][j]);
          }
        }
      }
    }
  }
}

// ---------------------------------------------------------------------------
extern "C" void kernel_launch(void* const* d_in, const int* in_sizes, int n_in,
                              void* d_out, int out_size, void* d_ws, size_t ws_size,
                              hipStream_t stream){
  const float* x  = (const float*)d_in[0];
  const float* rw = (const float*)d_in[1];
  const float* w1 = (const float*)d_in[2];
  const float* w2 = (const float*)d_in[3];
  const float* w3 = (const float*)d_in[4];
  float* out = (float*)d_out;

  char* ws = (char*)d_ws;
  size_t off = 0;
  unsigned short* xb  = (unsigned short*)(ws + off); off += (size_t)T_TOK*H_DIM*2;
  unsigned short* w1b = (unsigned short*)(ws + off); off += (size_t)E_NUM*F_DIM*H_DIM*2;
  unsigned short* w3b = (unsigned short*)(ws + off); off += (size_t)E_NUM*F_DIM*H_DIM*2;
  unsigned short* w2b = (unsigned short*)(ws + off); off += (size_t)E_NUM*H_DIM*F_DIM*2;
  unsigned short* hidden = (unsigned short*)(ws + off); off += (size_t)MAXROWS*F_DIM*2;
  int*   counts  = (int*)(ws + off); off += 64;
  int*   ts256   = (int*)(ws + off); off += 64;
  int*   cursors = (int*)(ws + off); off += 64;
  int*   topi    = (int*)(ws + off); off += (size_t)T_TOK*2*4;
  float* topv    = (float*)(ws + off); off += (size_t)T_TOK*2*4;
  int*   entries = (int*)(ws + off); off += (size_t)MAXROWS*4;

  hipFuncSetAttribute((const void*)k_ffn1,
                      hipFuncAttributeMaxDynamicSharedMemorySize, 131072);
  hipFuncSetAttribute((const void*)k_ffn2,
                      hipFuncAttributeMaxDynamicSharedMemorySize, 147456);

  hipMemsetAsync(counts, 0, 32, stream);
  hipMemsetAsync(out, 0, (size_t)out_size*sizeof(float), stream);

  k_router<<<T_TOK/32, 256, 0, stream>>>(x, rw, counts, topi, topv, xb);
  k_offsets<<<1, 64, 0, stream>>>(counts, ts256, cursors);
  k_fill<<<T_TOK/256, 256, 0, stream>>>(topi, ts256, cursors, entries);
  k_wcvt<<<3*2048, 256, 0, stream>>>(w1, w3, w2, w1b, w3b, w2b);

  k_ffn1<<<MAXT256*16, 512, 131072, stream>>>(xb, w1b, w3b, ts256, counts, entries, hidden);
  k_ffn2<<<MAXT256*8, 512, 147456, stream>>>(hidden, w2b, ts256, counts, entries, topv, out);
}